// Round 1
// baseline (95.138 us; speedup 1.0000x reference)
//
#include <hip/hip_runtime.h>
#include <cfloat>

// EmbeddingBag(mean) ++ EmbeddingBag(max) -> Linear(no bias)
// inputs: feat[T] i32, offs[B] i32 (sorted, offs[0]=0), W[100000][128] f32, L[128][256] f32
// out: [B][128] f32
//
// Bag b = tokens [offs[b], offs[b+1]) (offs[B]=T). Duplicate offsets -> empty
// bags (matches searchsorted 'right' - 1 semantics): count 0 -> mean=0, max=0.

constexpr int D     = 128;   // embedding dim
constexpr int TYPES = 128;   // linear out features
constexpr int BPB   = 8;     // bags per block

__global__ __launch_bounds__(256, 4)
void embbag_men_linear(const int* __restrict__ feat,
                       const int* __restrict__ offs,
                       const float* __restrict__ W,
                       const float* __restrict__ L,
                       float* __restrict__ out,
                       int T, int B)
{
    // men[bag][j]: j in [0,32) mean dims 4j..4j+3 ; j in [32,64) max dims
    __shared__ float4 men[BPB][64];
    __shared__ float4 red_s[8][32];
    __shared__ float4 red_m[8][32];
    __shared__ float  partial[BPB][TYPES];

    const int tid  = threadIdx.x;
    const int slot = tid >> 5;   // 0..7: token slot
    const int g    = tid & 31;   // dim group: dims 4g..4g+3
    const int bag0 = blockIdx.x * BPB;

    // ---------------- Phase A: per-bag mean+max gather ----------------
    for (int bb = 0; bb < BPB; ++bb) {
        const int bag = bag0 + bb;
        int start = 0, end = 0;
        if (bag < B) {
            start = offs[bag];
            end   = (bag + 1 < B) ? offs[bag + 1] : T;
        }

        float4 s4 = make_float4(0.f, 0.f, 0.f, 0.f);
        float4 m4 = make_float4(-FLT_MAX, -FLT_MAX, -FLT_MAX, -FLT_MAX);

        for (int i = start + slot; i < end; i += 8) {
            const int idx = feat[i];
            const float4 v =
                *reinterpret_cast<const float4*>(W + (size_t)idx * D + 4 * g);
            s4.x += v.x; s4.y += v.y; s4.z += v.z; s4.w += v.w;
            m4.x = fmaxf(m4.x, v.x);
            m4.y = fmaxf(m4.y, v.y);
            m4.z = fmaxf(m4.z, v.z);
            m4.w = fmaxf(m4.w, v.w);
        }
        red_s[slot][g] = s4;
        red_m[slot][g] = m4;
        __syncthreads();

        if (tid < 32) {
            float4 ts = red_s[0][tid];
            float4 tm = red_m[0][tid];
            #pragma unroll
            for (int s = 1; s < 8; ++s) {
                const float4 a = red_s[s][tid];
                const float4 b = red_m[s][tid];
                ts.x += a.x; ts.y += a.y; ts.z += a.z; ts.w += a.w;
                tm.x = fmaxf(tm.x, b.x); tm.y = fmaxf(tm.y, b.y);
                tm.z = fmaxf(tm.z, b.z); tm.w = fmaxf(tm.w, b.w);
            }
            const int  n     = end - start;
            const bool empty = (n <= 0);
            const float inv  = 1.0f / (float)(empty ? 1 : n);
            men[bb][tid] = make_float4(ts.x * inv, ts.y * inv,
                                       ts.z * inv, ts.w * inv);
            men[bb][32 + tid] = empty ? make_float4(0.f, 0.f, 0.f, 0.f)
                                      : tm;
        }
        __syncthreads();   // men written; red_* free for next bag
    }

    // ---------------- Phase B: out[bag][o] = sum_k men[bag][k]*L[o][k] ----
    // thread -> (o = output type, h = k-half). Register-block over 8 bags so
    // each L float4 is loaded once per block-half and used 8x.
    const int o = tid & (TYPES - 1);
    const int h = tid >> 7;   // 0 or 1

    float acc[BPB];
    #pragma unroll
    for (int b = 0; b < BPB; ++b) acc[b] = 0.f;

    const float* Lrow = L + (size_t)o * (2 * D) + h * D;
    #pragma unroll 8
    for (int k4 = 0; k4 < D / 4; ++k4) {
        const float4 lv = *reinterpret_cast<const float4*>(Lrow + 4 * k4);
        #pragma unroll
        for (int b = 0; b < BPB; ++b) {
            const float4 mv = men[b][h * 32 + k4];
            acc[b] = fmaf(lv.x, mv.x, acc[b]);
            acc[b] = fmaf(lv.y, mv.y, acc[b]);
            acc[b] = fmaf(lv.z, mv.z, acc[b]);
            acc[b] = fmaf(lv.w, mv.w, acc[b]);
        }
    }

    if (h == 1) {
        #pragma unroll
        for (int b = 0; b < BPB; ++b) partial[b][o] = acc[b];
    }
    __syncthreads();
    if (h == 0) {
        #pragma unroll
        for (int b = 0; b < BPB; ++b) {
            const int bag = bag0 + b;
            if (bag < B)
                out[(size_t)bag * TYPES + o] = acc[b] + partial[b][o];
        }
    }
}

extern "C" void kernel_launch(void* const* d_in, const int* in_sizes, int n_in,
                              void* d_out, int out_size, void* d_ws, size_t ws_size,
                              hipStream_t stream)
{
    const int*   feat = (const int*)d_in[0];
    const int*   offs = (const int*)d_in[1];
    const float* W    = (const float*)d_in[2];
    const float* L    = (const float*)d_in[3];
    float*       out  = (float*)d_out;

    const int T = in_sizes[0];
    const int B = in_sizes[1];
    const int grid = (B + BPB - 1) / BPB;
    embbag_men_linear<<<grid, 256, 0, stream>>>(feat, offs, W, L, out, T, B);
}

// Round 2
// 75.042 us; speedup vs baseline: 1.2678x; 1.2678x over previous
//
#include <hip/hip_runtime.h>
#include <cfloat>

// EmbeddingBag(mean) ++ EmbeddingBag(max) -> Linear(no bias)
// inputs: feat[T] i32, offs[B] i32 (sorted, offs[0]=0), W[100000][128] f32,
//         L[128][256] f32 ; out: [B][128] f32
// Bag b = tokens [offs[b], offs[b+1]) (offs[B]=T); empty bag -> mean=max=0.

constexpr int D     = 128;   // embedding dim
constexpr int TYPES = 128;   // linear out features
constexpr int BPB   = 4;     // bags per block == waves per block

__global__ __launch_bounds__(256, 8)
void embbag_men_linear(const int* __restrict__ feat,
                       const int* __restrict__ offs,
                       const float* __restrict__ W,
                       const float* __restrict__ L,
                       float* __restrict__ out,
                       int T, int B)
{
    // men[bag][j]: j in [0,32) mean dims 4j..4j+3 ; j in [32,64) max dims
    __shared__ float4 men[BPB][64];
    __shared__ float  partial[BPB][TYPES];

    const int tid  = threadIdx.x;
    const int wv   = tid >> 6;          // wave id 0..3  -> bag
    const int lane = tid & 63;
    const int slot = lane >> 5;         // 0..1 : token slot within wave
    const int g    = lane & 31;         // dim group: dims 4g..4g+3
    const int bag0 = blockIdx.x * BPB;
    const int bag  = bag0 + wv;

    // ---------------- Phase A: per-wave bag mean+max gather ----------------
    int start = 0, end = 0;
    if (bag < B) {
        start = offs[bag];
        end   = (bag + 1 < B) ? offs[bag + 1] : T;
    }

    float4 s4 = make_float4(0.f, 0.f, 0.f, 0.f);
    float4 m4 = make_float4(-FLT_MAX, -FLT_MAX, -FLT_MAX, -FLT_MAX);

    const float* __restrict__ Wg = W + 4 * g;

    int i = start + slot;
    // 4 tokens per lane-iteration: batch the index loads, keep 4 row-gathers
    // in flight per lane.
    for (; i + 6 < end; i += 8) {
        const int i0 = feat[i];
        const int i1 = feat[i + 2];
        const int i2 = feat[i + 4];
        const int i3 = feat[i + 6];
        const float4 v0 = *reinterpret_cast<const float4*>(Wg + (size_t)i0 * D);
        const float4 v1 = *reinterpret_cast<const float4*>(Wg + (size_t)i1 * D);
        const float4 v2 = *reinterpret_cast<const float4*>(Wg + (size_t)i2 * D);
        const float4 v3 = *reinterpret_cast<const float4*>(Wg + (size_t)i3 * D);
        s4.x += v0.x + v1.x + v2.x + v3.x;
        s4.y += v0.y + v1.y + v2.y + v3.y;
        s4.z += v0.z + v1.z + v2.z + v3.z;
        s4.w += v0.w + v1.w + v2.w + v3.w;
        m4.x = fmaxf(fmaxf(fmaxf(m4.x, v0.x), fmaxf(v1.x, v2.x)), v3.x);
        m4.y = fmaxf(fmaxf(fmaxf(m4.y, v0.y), fmaxf(v1.y, v2.y)), v3.y);
        m4.z = fmaxf(fmaxf(fmaxf(m4.z, v0.z), fmaxf(v1.z, v2.z)), v3.z);
        m4.w = fmaxf(fmaxf(fmaxf(m4.w, v0.w), fmaxf(v1.w, v2.w)), v3.w);
    }
    for (; i < end; i += 2) {
        const int idx = feat[i];
        const float4 v = *reinterpret_cast<const float4*>(Wg + (size_t)idx * D);
        s4.x += v.x; s4.y += v.y; s4.z += v.z; s4.w += v.w;
        m4.x = fmaxf(m4.x, v.x); m4.y = fmaxf(m4.y, v.y);
        m4.z = fmaxf(m4.z, v.z); m4.w = fmaxf(m4.w, v.w);
    }

    // reduce across the 2 slots (lane ^ 32), wave-local, no barrier
    s4.x += __shfl_xor(s4.x, 32); s4.y += __shfl_xor(s4.y, 32);
    s4.z += __shfl_xor(s4.z, 32); s4.w += __shfl_xor(s4.w, 32);
    m4.x = fmaxf(m4.x, __shfl_xor(m4.x, 32));
    m4.y = fmaxf(m4.y, __shfl_xor(m4.y, 32));
    m4.z = fmaxf(m4.z, __shfl_xor(m4.z, 32));
    m4.w = fmaxf(m4.w, __shfl_xor(m4.w, 32));

    if (lane < 32) {
        const int  n     = end - start;
        const bool empty = (n <= 0);
        const float inv  = 1.0f / (float)(empty ? 1 : n);
        men[wv][g]      = make_float4(s4.x * inv, s4.y * inv,
                                      s4.z * inv, s4.w * inv);
        men[wv][32 + g] = empty ? make_float4(0.f, 0.f, 0.f, 0.f) : m4;
    }
    __syncthreads();

    // ---------------- Phase B: out[bag][o] = sum_k men[bag][k]*L[o][k] ----
    // thread -> (o = output type, h = k-half); register-block over 4 bags.
    const int o = tid & (TYPES - 1);
    const int h = tid >> 7;   // 0 or 1

    float acc[BPB];
    #pragma unroll
    for (int b = 0; b < BPB; ++b) acc[b] = 0.f;

    const float* Lrow = L + (size_t)o * (2 * D) + h * D;
    #pragma unroll 8
    for (int k4 = 0; k4 < D / 4; ++k4) {
        const float4 lv = *reinterpret_cast<const float4*>(Lrow + 4 * k4);
        #pragma unroll
        for (int b = 0; b < BPB; ++b) {
            const float4 mv = men[b][h * 32 + k4];
            acc[b] = fmaf(lv.x, mv.x, acc[b]);
            acc[b] = fmaf(lv.y, mv.y, acc[b]);
            acc[b] = fmaf(lv.z, mv.z, acc[b]);
            acc[b] = fmaf(lv.w, mv.w, acc[b]);
        }
    }

    if (h == 1) {
        #pragma unroll
        for (int b = 0; b < BPB; ++b) partial[b][o] = acc[b];
    }
    __syncthreads();
    if (h == 0) {
        #pragma unroll
        for (int b = 0; b < BPB; ++b) {
            const int bg = bag0 + b;
            if (bg < B)
                out[(size_t)bg * TYPES + o] = acc[b] + partial[b][o];
        }
    }
}

extern "C" void kernel_launch(void* const* d_in, const int* in_sizes, int n_in,
                              void* d_out, int out_size, void* d_ws, size_t ws_size,
                              hipStream_t stream)
{
    const int*   feat = (const int*)d_in[0];
    const int*   offs = (const int*)d_in[1];
    const float* W    = (const float*)d_in[2];
    const float* L    = (const float*)d_in[3];
    float*       out  = (float*)d_out;

    const int T = in_sizes[0];
    const int B = in_sizes[1];
    const int grid = (B + BPB - 1) / BPB;
    embbag_men_linear<<<grid, 256, 0, stream>>>(feat, offs, W, L, out, T, B);
}

// Round 3
// 67.060 us; speedup vs baseline: 1.4187x; 1.1190x over previous
//
#include <hip/hip_runtime.h>
#include <cfloat>

// EmbeddingBag(mean) ++ EmbeddingBag(max) -> Linear(no bias)
// feat[T] i32, offs[B] i32 (sorted, offs[0]=0), W[100000][128] f32,
// L[128][256] f32 ; out: [B][128] f32
// Bag b = tokens [offs[b], offs[b+1]) (offs[B]=T); empty bag -> mean=max=0.

constexpr int D     = 128;   // embedding dim
constexpr int TYPES = 128;   // linear out features
constexpr int BPB   = 4;     // bags per block
constexpr int WPB   = 2;     // waves per bag
constexpr int BLOCK = 512;   // 8 waves

__global__ __launch_bounds__(BLOCK, 8)
void embbag_men_linear(const int* __restrict__ feat,
                       const int* __restrict__ offs,
                       const float* __restrict__ W,
                       const float* __restrict__ L,
                       float* __restrict__ out,
                       int T, int B)
{
    // men[bag][j]: j in [0,32) mean dims 4j..4j+3 ; j in [32,64) max dims
    __shared__ float4 men[BPB][64];
    __shared__ float4 redS[BPB][WPB][32];
    __shared__ float4 redM[BPB][WPB][32];
    __shared__ float  partial[3][BPB][TYPES];

    const int tid  = threadIdx.x;
    const int wv   = tid >> 6;        // wave 0..7
    const int lane = tid & 63;
    const int bi   = wv >> 1;         // bag slot in block: 0..3
    const int wh   = wv & 1;          // which half-wave-pair of the bag
    const int slot = lane >> 5;       // 0..1
    const int g    = lane & 31;       // dim group: dims 4g..4g+3
    const int bag0 = blockIdx.x * BPB;
    const int bag  = bag0 + bi;

    // ------------- Phase A: gather, 2 waves per bag, 4 contiguous quarters --
    int start = 0, end = 0;
    if (bag < B) {
        start = offs[bag];
        end   = (bag + 1 < B) ? offs[bag + 1] : T;
    }
    const int n  = end - start;
    const int q  = wh * 2 + slot;              // quarter 0..3
    const int qa = start + (n * q) / 4;
    const int qb = start + (n * (q + 1)) / 4;

    float4 s4 = make_float4(0.f, 0.f, 0.f, 0.f);
    float4 m4 = make_float4(-FLT_MAX, -FLT_MAX, -FLT_MAX, -FLT_MAX);
    const float* __restrict__ Wg = W + 4 * g;

    int i = qa;
    // 8 row-gathers in flight per lane
    for (; i + 8 <= qb; i += 8) {
        int idx[8];
        #pragma unroll
        for (int j = 0; j < 8; ++j) idx[j] = feat[i + j];
        float4 v[8];
        #pragma unroll
        for (int j = 0; j < 8; ++j)
            v[j] = *reinterpret_cast<const float4*>(Wg + (size_t)idx[j] * D);
        #pragma unroll
        for (int j = 0; j < 8; ++j) {
            s4.x += v[j].x; s4.y += v[j].y; s4.z += v[j].z; s4.w += v[j].w;
            m4.x = fmaxf(m4.x, v[j].x); m4.y = fmaxf(m4.y, v[j].y);
            m4.z = fmaxf(m4.z, v[j].z); m4.w = fmaxf(m4.w, v[j].w);
        }
    }
    for (; i < qb; ++i) {
        const int idx = feat[i];
        const float4 v = *reinterpret_cast<const float4*>(Wg + (size_t)idx * D);
        s4.x += v.x; s4.y += v.y; s4.z += v.z; s4.w += v.w;
        m4.x = fmaxf(m4.x, v.x); m4.y = fmaxf(m4.y, v.y);
        m4.z = fmaxf(m4.z, v.z); m4.w = fmaxf(m4.w, v.w);
    }

    // reduce the 2 slots within the wave (lane ^ 32)
    s4.x += __shfl_xor(s4.x, 32); s4.y += __shfl_xor(s4.y, 32);
    s4.z += __shfl_xor(s4.z, 32); s4.w += __shfl_xor(s4.w, 32);
    m4.x = fmaxf(m4.x, __shfl_xor(m4.x, 32));
    m4.y = fmaxf(m4.y, __shfl_xor(m4.y, 32));
    m4.z = fmaxf(m4.z, __shfl_xor(m4.z, 32));
    m4.w = fmaxf(m4.w, __shfl_xor(m4.w, 32));

    if (lane < 32) {
        redS[bi][wh][g] = s4;
        redM[bi][wh][g] = m4;
    }
    __syncthreads();

    // combine the 2 waves of each bag; compute mean / masked max
    if (wh == 0 && lane < 32) {
        const float4 a0 = redS[bi][0][g], a1 = redS[bi][1][g];
        const float4 b0 = redM[bi][0][g], b1 = redM[bi][1][g];
        const bool  empty = (n <= 0);
        const float inv   = 1.0f / (float)(empty ? 1 : n);
        men[bi][g] = make_float4((a0.x + a1.x) * inv, (a0.y + a1.y) * inv,
                                 (a0.z + a1.z) * inv, (a0.w + a1.w) * inv);
        men[bi][32 + g] = empty
            ? make_float4(0.f, 0.f, 0.f, 0.f)
            : make_float4(fmaxf(b0.x, b1.x), fmaxf(b0.y, b1.y),
                          fmaxf(b0.z, b1.z), fmaxf(b0.w, b1.w));
    }
    __syncthreads();

    // ------------- Phase B: out[bag][o] = sum_k men[bag][k] * L[o][k] ------
    // thread -> (o = out feature, h = k-quarter of 64); register-block 4 bags.
    const int o = tid & (TYPES - 1);
    const int h = tid >> 7;    // 0..3

    float acc[BPB];
    #pragma unroll
    for (int b = 0; b < BPB; ++b) acc[b] = 0.f;

    const float* Lrow = L + (size_t)o * (2 * D) + h * 64;
    #pragma unroll
    for (int k4 = 0; k4 < 16; ++k4) {
        const float4 lv = *reinterpret_cast<const float4*>(Lrow + 4 * k4);
        #pragma unroll
        for (int b = 0; b < BPB; ++b) {
            const float4 mv = men[b][h * 16 + k4];
            acc[b] = fmaf(lv.x, mv.x, acc[b]);
            acc[b] = fmaf(lv.y, mv.y, acc[b]);
            acc[b] = fmaf(lv.z, mv.z, acc[b]);
            acc[b] = fmaf(lv.w, mv.w, acc[b]);
        }
    }

    if (h > 0) {
        #pragma unroll
        for (int b = 0; b < BPB; ++b) partial[h - 1][b][o] = acc[b];
    }
    __syncthreads();
    if (h == 0) {
        #pragma unroll
        for (int b = 0; b < BPB; ++b) {
            const int bg = bag0 + b;
            if (bg < B)
                out[(size_t)bg * TYPES + o] =
                    acc[b] + partial[0][b][o] + partial[1][b][o] + partial[2][b][o];
        }
    }
}

extern "C" void kernel_launch(void* const* d_in, const int* in_sizes, int n_in,
                              void* d_out, int out_size, void* d_ws, size_t ws_size,
                              hipStream_t stream)
{
    const int*   feat = (const int*)d_in[0];
    const int*   offs = (const int*)d_in[1];
    const float* W    = (const float*)d_in[2];
    const float* L    = (const float*)d_in[3];
    float*       out  = (float*)d_out;

    const int T = in_sizes[0];
    const int B = in_sizes[1];
    const int grid = (B + BPB - 1) / BPB;
    embbag_men_linear<<<grid, BLOCK, 0, stream>>>(feat, offs, W, L, out, T, B);
}

// Round 4
// 62.186 us; speedup vs baseline: 1.5299x; 1.0784x over previous
//
#include <hip/hip_runtime.h>
#include <cfloat>

// EmbeddingBag(mean) ++ EmbeddingBag(max) -> Linear(no bias)
// feat[T] i32, offs[B] i32 (sorted, offs[0]=0), W[100000][128] f32,
// L[128][256] f32 ; out: [B][128] f32
// Bag b = tokens [offs[b], offs[b+1]) (offs[B]=T); empty bag -> mean=max=0.

constexpr int D     = 128;   // embedding dim
constexpr int TYPES = 128;   // linear out features
constexpr int BPB   = 4;     // bags per block
constexpr int WPB   = 2;     // waves per bag
constexpr int BLOCK = 512;   // 8 waves

__global__ __launch_bounds__(BLOCK, 8)
void embbag_men_linear(const int* __restrict__ feat,
                       const int* __restrict__ offs,
                       const float* __restrict__ W,
                       const float* __restrict__ L,
                       float* __restrict__ out,
                       int T, int B)
{
    // men[bag][j]: j in [0,32) mean dims 4j..4j+3 ; j in [32,64) max dims
    __shared__ float4 men[BPB][64];
    __shared__ float4 redS[BPB][WPB][32];
    __shared__ float4 redM[BPB][WPB][32];
    __shared__ float  partial[3][BPB][TYPES];

    const int tid  = threadIdx.x;
    const int wv   = tid >> 6;        // wave 0..7
    const int lane = tid & 63;
    const int bi   = wv >> 1;         // bag slot in block: 0..3
    const int wh   = wv & 1;          // which wave of the bag's pair
    const int slot = lane >> 5;       // 0..1
    const int g    = lane & 31;       // dim group: dims 4g..4g+3
    const int bag0 = blockIdx.x * BPB;
    const int bag  = bag0 + bi;

    // ------------- Phase A: gather, 2 waves per bag, 4 contiguous quarters --
    int start = 0, end = 0;
    if (bag < B) {
        start = offs[bag];
        end   = (bag + 1 < B) ? offs[bag + 1] : T;
    }
    const int n  = end - start;
    const int q  = wh * 2 + slot;              // quarter 0..3
    const int qa = start + (n * q) / 4;
    const int qb = start + (n * (q + 1)) / 4;

    float4 s4 = make_float4(0.f, 0.f, 0.f, 0.f);
    float4 m4 = make_float4(-FLT_MAX, -FLT_MAX, -FLT_MAX, -FLT_MAX);
    const float* __restrict__ Wg = W + 4 * g;

    int i = qa;
    // full 8-deep iterations: 8 row-gathers in flight per lane
    for (; i + 8 <= qb; i += 8) {
        int idx[8];
        #pragma unroll
        for (int j = 0; j < 8; ++j) idx[j] = feat[i + j];
        float4 v[8];
        #pragma unroll
        for (int j = 0; j < 8; ++j)
            v[j] = *reinterpret_cast<const float4*>(Wg + (size_t)idx[j] * D);
        #pragma unroll
        for (int j = 0; j < 8; ++j) {
            s4.x += v[j].x; s4.y += v[j].y; s4.z += v[j].z; s4.w += v[j].w;
            m4.x = fmaxf(m4.x, v[j].x); m4.y = fmaxf(m4.y, v[j].y);
            m4.z = fmaxf(m4.z, v[j].z); m4.w = fmaxf(m4.w, v[j].w);
        }
    }
    // one predicated 8-wide tail iteration (no serial cleanup chain)
    if (i < qb) {
        const int rem = qb - i;            // 1..7
        int idx[8];
        #pragma unroll
        for (int j = 0; j < 8; ++j)
            idx[j] = feat[j < rem ? i + j : qb - 1];
        float4 v[8];
        #pragma unroll
        for (int j = 0; j < 8; ++j)
            v[j] = *reinterpret_cast<const float4*>(Wg + (size_t)idx[j] * D);
        #pragma unroll
        for (int j = 0; j < 8; ++j) {
            const bool val = (j < rem);
            const float vx = val ? v[j].x : 0.f;
            const float vy = val ? v[j].y : 0.f;
            const float vz = val ? v[j].z : 0.f;
            const float vw = val ? v[j].w : 0.f;
            s4.x += vx; s4.y += vy; s4.z += vz; s4.w += vw;
            m4.x = fmaxf(m4.x, val ? v[j].x : -FLT_MAX);
            m4.y = fmaxf(m4.y, val ? v[j].y : -FLT_MAX);
            m4.z = fmaxf(m4.z, val ? v[j].z : -FLT_MAX);
            m4.w = fmaxf(m4.w, val ? v[j].w : -FLT_MAX);
        }
    }

    // reduce the 2 slots within the wave (lane ^ 32)
    s4.x += __shfl_xor(s4.x, 32); s4.y += __shfl_xor(s4.y, 32);
    s4.z += __shfl_xor(s4.z, 32); s4.w += __shfl_xor(s4.w, 32);
    m4.x = fmaxf(m4.x, __shfl_xor(m4.x, 32));
    m4.y = fmaxf(m4.y, __shfl_xor(m4.y, 32));
    m4.z = fmaxf(m4.z, __shfl_xor(m4.z, 32));
    m4.w = fmaxf(m4.w, __shfl_xor(m4.w, 32));

    if (lane < 32) {
        redS[bi][wh][g] = s4;
        redM[bi][wh][g] = m4;
    }
    __syncthreads();

    // combine the 2 waves of each bag; compute mean / masked max
    if (wh == 0 && lane < 32) {
        const float4 a0 = redS[bi][0][g], a1 = redS[bi][1][g];
        const float4 b0 = redM[bi][0][g], b1 = redM[bi][1][g];
        const bool  empty = (n <= 0);
        const float inv   = 1.0f / (float)(empty ? 1 : n);
        men[bi][g] = make_float4((a0.x + a1.x) * inv, (a0.y + a1.y) * inv,
                                 (a0.z + a1.z) * inv, (a0.w + a1.w) * inv);
        men[bi][32 + g] = empty
            ? make_float4(0.f, 0.f, 0.f, 0.f)
            : make_float4(fmaxf(b0.x, b1.x), fmaxf(b0.y, b1.y),
                          fmaxf(b0.z, b1.z), fmaxf(b0.w, b1.w));
    }
    __syncthreads();

    // ------------- Phase B: out[bag][o] = sum_k men[bag][k] * L[o][k] ------
    // thread -> (o = out feature, h = k-quarter of 64); register-block 4 bags.
    const int o = tid & (TYPES - 1);
    const int h = tid >> 7;    // 0..3

    float acc[BPB];
    #pragma unroll
    for (int b = 0; b < BPB; ++b) acc[b] = 0.f;

    const float* Lrow = L + (size_t)o * (2 * D) + h * 64;
    #pragma unroll
    for (int k4 = 0; k4 < 16; ++k4) {
        const float4 lv = *reinterpret_cast<const float4*>(Lrow + 4 * k4);
        #pragma unroll
        for (int b = 0; b < BPB; ++b) {
            const float4 mv = men[b][h * 16 + k4];
            acc[b] = fmaf(lv.x, mv.x, acc[b]);
            acc[b] = fmaf(lv.y, mv.y, acc[b]);
            acc[b] = fmaf(lv.z, mv.z, acc[b]);
            acc[b] = fmaf(lv.w, mv.w, acc[b]);
        }
    }

    if (h > 0) {
        #pragma unroll
        for (int b = 0; b < BPB; ++b) partial[h - 1][b][o] = acc[b];
    }
    __syncthreads();
    if (h == 0) {
        #pragma unroll
        for (int b = 0; b < BPB; ++b) {
            const int bg = bag0 + b;
            if (bg < B)
                out[(size_t)bg * TYPES + o] =
                    acc[b] + partial[0][b][o] + partial[1][b][o] + partial[2][b][o];
        }
    }
}

extern "C" void kernel_launch(void* const* d_in, const int* in_sizes, int n_in,
                              void* d_out, int out_size, void* d_ws, size_t ws_size,
                              hipStream_t stream)
{
    const int*   feat = (const int*)d_in[0];
    const int*   offs = (const int*)d_in[1];
    const float* W    = (const float*)d_in[2];
    const float* L    = (const float*)d_in[3];
    float*       out  = (float*)d_out;

    const int T = in_sizes[0];
    const int B = in_sizes[1];
    const int grid = (B + BPB - 1) / BPB;
    embbag_men_linear<<<grid, BLOCK, 0, stream>>>(feat, offs, W, L, out, T, B);
}